// Round 6
// baseline (1023.169 us; speedup 1.0000x reference)
//
#include <hip/hip_runtime.h>
#include <math.h>

#define N_USERS 100000
#define N_ITEMS 50000
#define N_NODES 150000
#define EMB 64
#define NI 128
#define NUM_EDGES 4000000
#define NPAD 150016            // 586 * 256
#define NB 586                 // buckets of 256 nodes
#define BSTRIDE 8192           // fixed slots per bucket (mean 6827, sigma 83 -> 16.5 sigma)
#define ETILE 4096
#define EGRID ((NUM_EDGES + ETILE - 1) / ETILE)   // 977
#define SW 68                  // Wt (col-major W) LDS row stride, floats
#define SV 132                 // W2 (row-major W) LDS row stride, floats

__device__ __forceinline__ unsigned short f2bf(float f) {
    unsigned int u = __float_as_uint(f);
    u += 0x7FFFu + ((u >> 16) & 1u);
    return (unsigned short)(u >> 16);
}

// ---- bucket scatter: block-aggregated reservations into fixed-stride buckets ----
// packs (h&255)<<18 | t ; gcur[b] counts within bucket, slot = b*BSTRIDE + res.

__global__ __launch_bounds__(256) void bucket_scatter(const int* __restrict__ h,
                                                      const int* __restrict__ t,
                                                      int* __restrict__ gcur,
                                                      unsigned int* __restrict__ ebuf) {
    __shared__ int lc[NB];
    __shared__ int lbase[NB];
    __shared__ int lcur[NB];
    int tid = threadIdx.x;
    for (int i = tid; i < NB; i += 256) lc[i] = 0;
    __syncthreads();
    int base = blockIdx.x * ETILE;
#pragma unroll
    for (int k = 0; k < ETILE / 256; ++k) {
        int idx = base + k * 256 + tid;
        if (idx < NUM_EDGES) atomicAdd(&lc[h[idx] >> 8], 1);
    }
    __syncthreads();
    for (int i = tid; i < NB; i += 256) {
        int c = lc[i];
        lbase[i] = c ? (i * BSTRIDE + atomicAdd(&gcur[i], c)) : 0;
        lcur[i] = 0;
    }
    __syncthreads();
#pragma unroll
    for (int k = 0; k < ETILE / 256; ++k) {
        int idx = base + k * 256 + tid;
        if (idx < NUM_EDGES) {
            int hh = h[idx], tt = t[idx];
            int b = hh >> 8;
            int p = lbase[b] + atomicAdd(&lcur[b], 1);
            // defensive clamp: never write outside this bucket's fixed region
            int lim = b * BSTRIDE + BSTRIDE - 1;
            p = (p <= lim) ? p : lim;
            ebuf[p] = ((unsigned int)(hh & 255) << 18) | (unsigned int)tt;
        }
    }
}

// ---- per-bucket in-LDS counting sort -> row-sorted col, rmeta=(start,count), dinv ----

__global__ __launch_bounds__(256) void bucket_csr(const int* __restrict__ gcur,
                                                  unsigned int* __restrict__ ebuf,
                                                  int2* __restrict__ rmeta,
                                                  float* __restrict__ dinv) {
    __shared__ unsigned int in_s[BSTRIDE];
    __shared__ unsigned int out_s[BSTRIDE];
    __shared__ int cnt_s[256];
    __shared__ int base_s[256];
    __shared__ int sc[256];
    int b = blockIdx.x, tid = threadIdx.x;
    int s = b * BSTRIDE;
    int n = gcur[b];
    if (n > BSTRIDE) n = BSTRIDE;

    for (int i = tid; i < n; i += 256) in_s[i] = ebuf[s + i];
    cnt_s[tid] = 0;
    __syncthreads();
    for (int i = tid; i < n; i += 256) atomicAdd(&cnt_s[in_s[i] >> 18], 1);
    __syncthreads();

    int c = cnt_s[tid];
    sc[tid] = c;
    __syncthreads();
    for (int off = 1; off < 256; off <<= 1) {
        int tv = (tid >= off) ? sc[tid - off] : 0;
        __syncthreads();
        sc[tid] += tv;
        __syncthreads();
    }
    int excl = sc[tid] - c;
    base_s[tid] = excl;
    int node = (b << 8) + tid;
    rmeta[node] = make_int2(s + excl, c);
    dinv[node] = (c > 0) ? rsqrtf((float)c) : 0.0f;
    cnt_s[tid] = 0;      // reuse as cursors
    __syncthreads();

    for (int i = tid; i < n; i += 256) {
        unsigned int q = in_s[i];
        int hl = (int)(q >> 18);
        int p = base_s[hl] + atomicAdd(&cnt_s[hl], 1);
        out_s[p] = q & 0x3FFFFu;
    }
    __syncthreads();
    for (int i = tid; i < n; i += 256) ebuf[s + i] = out_s[i];
}

// ---- init: ebf = bf16(concat(user,item)); acc(d_out) = concat fp32 ----

__global__ void init_kernel(const float4* __restrict__ ue4, const float4* __restrict__ ie4,
                            uint2* __restrict__ ebf4, float4* __restrict__ out4) {
    int i = blockIdx.x * blockDim.x + threadIdx.x;   // over float4 units
    const int uelems = N_USERS * EMB / 4;
    const int total  = N_NODES * EMB / 4;
    if (i < total) {
        float4 v = (i < uelems) ? ue4[i] : ie4[i - uelems];
        out4[i] = v;
        unsigned int p0 = ((unsigned int)f2bf(v.y) << 16) | f2bf(v.x);
        unsigned int p1 = ((unsigned int)f2bf(v.w) << 16) | f2bf(v.z);
        ebf4[i] = make_uint2(p0, p1);
    }
}

// ---- fused SpMM (bf16 CSR gather, 4 edges/wave-pass) + intent head + combine ----
// Block = 512 (8 waves, 1 row each per iter). LDS: W twice (b128-friendly pads).
// Gather: lane = (sub=lane>>4 edge slot, lq=lane&15 dim-quad), dwordx2 = 4 bf16.

__global__ __launch_bounds__(512) void spmm_intent(const int2* __restrict__ rmeta,
                                                   const unsigned int* __restrict__ col,
                                                   const float* __restrict__ dinv,
                                                   const unsigned short* __restrict__ ebf,
                                                   unsigned short* __restrict__ ebfout,
                                                   const float* __restrict__ W,
                                                   float* __restrict__ acc, float scale) {
    __shared__ __align__(16) float Wt[NI * SW];   // Wt[c*SW+d] = W[d][c]  (34816 B)
    __shared__ __align__(16) float W2[EMB * SV];  // W2[d*SV+c] = W[d][c]  (33792 B)
    __shared__ __align__(16) float pr[8][NI];
    __shared__ __align__(16) float er[8][EMB];
    int tid = threadIdx.x;
    for (int i = tid; i < EMB * NI; i += 512) {
        int d = i >> 7, c = i & 127;
        float v = W[i];
        Wt[c * SW + d] = v;
        W2[d * SV + c] = v;
    }
    __syncthreads();

    int w = tid >> 6, lane = tid & 63;
    int sub = lane >> 4, lq = lane & 15;
    float* erw = er[w];
    float* pw  = pr[w];
    const float* w0p = &Wt[lane * SW];
    const float* w1p = &Wt[(lane + 64) * SW];
    const float* w2p = &W2[lane * SV];

    for (int row = blockIdx.x * 8 + w; row < N_NODES; row += gridDim.x * 8) {
        int2 rm = rmeta[row];
        int s = rm.x, e = rm.x + rm.y;

        float4 a = make_float4(0.f, 0.f, 0.f, 0.f);
#pragma unroll 2
        for (int i0 = s; i0 < e; i0 += 4) {
            int i = i0 + sub;
            bool ok = (i < e);
            int ii = ok ? i : i0;
            int c = (int)(col[ii] & 0x3FFFFu);
            float gv = ok ? dinv[c] : 0.0f;
            uint2 u = *(const uint2*)(ebf + ((size_t)c << 6) + (lq << 2));
            a.x = fmaf(gv, __uint_as_float(u.x << 16), a.x);
            a.y = fmaf(gv, __uint_as_float(u.x & 0xFFFF0000u), a.y);
            a.z = fmaf(gv, __uint_as_float(u.y << 16), a.z);
            a.w = fmaf(gv, __uint_as_float(u.y & 0xFFFF0000u), a.w);
        }
        // reduce the 4 edge-slot partials (lanes lq, lq+16, lq+32, lq+48)
        a.x += __shfl_xor(a.x, 16); a.y += __shfl_xor(a.y, 16);
        a.z += __shfl_xor(a.z, 16); a.w += __shfl_xor(a.w, 16);
        a.x += __shfl_xor(a.x, 32); a.y += __shfl_xor(a.y, 32);
        a.z += __shfl_xor(a.z, 32); a.w += __shfl_xor(a.w, 32);
        // transpose to lane=dim: dim d lives at lane (d>>2), component (d&3)
        int src = lane >> 2;
        float vx = __shfl(a.x, src), vy = __shfl(a.y, src);
        float vz = __shfl(a.z, src), vw = __shfl(a.w, src);
        int mm = lane & 3;
        float gsum = (mm == 0) ? vx : (mm == 1) ? vy : (mm == 2) ? vz : vw;
        float gnnv = gsum * dinv[row];

        // intent scores from own bf16 embedding
        float eo = __uint_as_float((unsigned int)ebf[(size_t)row * EMB + lane] << 16);
        erw[lane] = eo;
        float s0 = 0.f, s1 = 0.f;
#pragma unroll
        for (int d = 0; d < EMB; d += 4) {
            float4 ev = *(const float4*)&erw[d];     // b128 broadcast
            float4 wa = *(const float4*)&w0p[d];     // b128, stride-68 rows
            float4 wb = *(const float4*)&w1p[d];
            s0 = fmaf(ev.x, wa.x, s0); s0 = fmaf(ev.y, wa.y, s0);
            s0 = fmaf(ev.z, wa.z, s0); s0 = fmaf(ev.w, wa.w, s0);
            s1 = fmaf(ev.x, wb.x, s1); s1 = fmaf(ev.y, wb.y, s1);
            s1 = fmaf(ev.z, wb.z, s1); s1 = fmaf(ev.w, wb.w, s1);
        }
        float m = fmaxf(s0, s1);
        for (int o = 32; o > 0; o >>= 1) m = fmaxf(m, __shfl_xor(m, o));
        float e0 = __expf(s0 - m), e1 = __expf(s1 - m);
        float sum = e0 + e1;
        for (int o = 32; o > 0; o >>= 1) sum += __shfl_xor(sum, o);
        float inv = 1.0f / sum;
        pw[lane]      = e0 * inv;
        pw[lane + 64] = e1 * inv;

        float o = 0.f;
#pragma unroll
        for (int c = 0; c < NI; c += 4) {
            float4 pv = *(const float4*)&pw[c];      // b128 broadcast
            float4 wv = *(const float4*)&w2p[c];     // b128, stride-132 rows
            o = fmaf(pv.x, wv.x, o); o = fmaf(pv.y, wv.y, o);
            o = fmaf(pv.z, wv.z, o); o = fmaf(pv.w, wv.w, o);
        }

        size_t idx = (size_t)row * EMB + lane;
        float nv = gnnv + o;
        ebfout[idx] = f2bf(nv);
        acc[idx] = (acc[idx] + nv) * scale;
    }
}

// ---- launch ----

extern "C" void kernel_launch(void* const* d_in, const int* in_sizes, int n_in,
                              void* d_out, int out_size, void* d_ws, size_t ws_size,
                              hipStream_t stream) {
    const float* ue = (const float*)d_in[0];
    const float* ie = (const float*)d_in[1];
    const float* W  = (const float*)d_in[2];
    const int*   h  = (const int*)d_in[3];
    const int*   t  = (const int*)d_in[4];
    float* out = (float*)d_out;

    // workspace (4-byte units), ~60 MB total
    int*            gcur  = (int*)d_ws;                         // 1024 (NB used)
    int2*           rmeta = (int2*)(gcur + 1024);               // NPAD int2
    float*          dinv  = (float*)(rmeta + NPAD);             // NPAD
    unsigned int*   ebuf  = (unsigned int*)(dinv + NPAD);       // NB*BSTRIDE = 4,800,512
    unsigned short* ebfA  = (unsigned short*)(ebuf + NB * BSTRIDE);   // NPAD*64 ushort
    unsigned short* ebfB  = ebfA + (size_t)NPAD * EMB;                // NPAD*64 ushort

    hipMemsetAsync(gcur, 0, NB * sizeof(int), stream);
    bucket_scatter<<<EGRID, 256, 0, stream>>>(h, t, gcur, ebuf);
    bucket_csr<<<NB, 256, 0, stream>>>(gcur, ebuf, rmeta, dinv);
    init_kernel<<<(N_NODES * EMB / 4 + 255) / 256, 256, 0, stream>>>(
        (const float4*)ue, (const float4*)ie, (uint2*)ebfA, (float4*)out);

    const unsigned int* col = ebuf;
    spmm_intent<<<1024, 512, 0, stream>>>(rmeta, col, dinv, ebfA, ebfB, W, out, 1.0f);
    spmm_intent<<<1024, 512, 0, stream>>>(rmeta, col, dinv, ebfB, ebfA, W, out, 1.0f / 3.0f);
}

// Round 7
// 900.829 us; speedup vs baseline: 1.1358x; 1.1358x over previous
//
#include <hip/hip_runtime.h>
#include <math.h>

#define N_USERS 100000
#define N_ITEMS 50000
#define N_NODES 150000
#define EMB 64
#define NI 128
#define NUM_EDGES 4000000
#define NPAD 150016            // 586 * 256
#define NB 586                 // buckets of 256 nodes
#define BSTRIDE 8192           // fixed slots per bucket (mean 6827, sigma ~83)
#define ETILE 4096
#define EGRID ((NUM_EDGES + ETILE - 1) / ETILE)   // 977
#define STW 34                 // Wt packed stride in dwords (32 data + 2 pad)
#define STV 66                 // W2 packed stride in dwords (64 data + 2 pad)

__device__ __forceinline__ unsigned short f2bf(float f) {
    unsigned int u = __float_as_uint(f);
    u += 0x7FFFu + ((u >> 16) & 1u);
    return (unsigned short)(u >> 16);
}
__device__ __forceinline__ float bflo(unsigned int u) { return __uint_as_float(u << 16); }
__device__ __forceinline__ float bfhi(unsigned int u) { return __uint_as_float(u & 0xFFFF0000u); }

// ---- bucket scatter: block-aggregated reservations into fixed-stride buckets ----

__global__ __launch_bounds__(256) void bucket_scatter(const int* __restrict__ h,
                                                      const int* __restrict__ t,
                                                      int* __restrict__ gcur,
                                                      unsigned int* __restrict__ ebuf) {
    __shared__ int lc[NB];
    __shared__ int lbase[NB];
    __shared__ int lcur[NB];
    int tid = threadIdx.x;
    for (int i = tid; i < NB; i += 256) lc[i] = 0;
    __syncthreads();
    int base = blockIdx.x * ETILE;
#pragma unroll
    for (int k = 0; k < ETILE / 256; ++k) {
        int idx = base + k * 256 + tid;
        if (idx < NUM_EDGES) atomicAdd(&lc[h[idx] >> 8], 1);
    }
    __syncthreads();
    for (int i = tid; i < NB; i += 256) {
        int c = lc[i];
        lbase[i] = c ? (i * BSTRIDE + atomicAdd(&gcur[i], c)) : 0;
        lcur[i] = 0;
    }
    __syncthreads();
#pragma unroll
    for (int k = 0; k < ETILE / 256; ++k) {
        int idx = base + k * 256 + tid;
        if (idx < NUM_EDGES) {
            int hh = h[idx], tt = t[idx];
            int b = hh >> 8;
            int p = lbase[b] + atomicAdd(&lcur[b], 1);
            int lim = b * BSTRIDE + BSTRIDE - 1;
            p = (p <= lim) ? p : lim;
            ebuf[p] = ((unsigned int)(hh & 255) << 18) | (unsigned int)tt;
        }
    }
}

// ---- per-bucket in-LDS counting sort -> row-sorted col, rmeta=(start,count), dinv ----

__global__ __launch_bounds__(256) void bucket_csr(const int* __restrict__ gcur,
                                                  unsigned int* __restrict__ ebuf,
                                                  int2* __restrict__ rmeta,
                                                  float* __restrict__ dinv) {
    __shared__ unsigned int in_s[BSTRIDE];
    __shared__ unsigned int out_s[BSTRIDE];
    __shared__ int cnt_s[256];
    __shared__ int base_s[256];
    __shared__ int sc[256];
    int b = blockIdx.x, tid = threadIdx.x;
    int s = b * BSTRIDE;
    int n = gcur[b];
    if (n > BSTRIDE) n = BSTRIDE;

    for (int i = tid; i < n; i += 256) in_s[i] = ebuf[s + i];
    cnt_s[tid] = 0;
    __syncthreads();
    for (int i = tid; i < n; i += 256) atomicAdd(&cnt_s[in_s[i] >> 18], 1);
    __syncthreads();

    int c = cnt_s[tid];
    sc[tid] = c;
    __syncthreads();
    for (int off = 1; off < 256; off <<= 1) {
        int tv = (tid >= off) ? sc[tid - off] : 0;
        __syncthreads();
        sc[tid] += tv;
        __syncthreads();
    }
    int excl = sc[tid] - c;
    base_s[tid] = excl;
    int node = (b << 8) + tid;
    rmeta[node] = make_int2(s + excl, c);
    dinv[node] = (c > 0) ? rsqrtf((float)c) : 0.0f;
    cnt_s[tid] = 0;
    __syncthreads();

    for (int i = tid; i < n; i += 256) {
        unsigned int q = in_s[i];
        int hl = (int)(q >> 18);
        int p = base_s[hl] + atomicAdd(&cnt_s[hl], 1);
        out_s[p] = q & 0x3FFFFu;    // pure t index
    }
    __syncthreads();
    for (int i = tid; i < n; i += 256) ebuf[s + i] = out_s[i];
}

// ---- init: ebf = bf16(concat(user,item)); acc(d_out) = concat fp32 ----

__global__ void init_kernel(const float4* __restrict__ ue4, const float4* __restrict__ ie4,
                            uint2* __restrict__ ebf4, float4* __restrict__ out4) {
    int i = blockIdx.x * blockDim.x + threadIdx.x;
    const int uelems = N_USERS * EMB / 4;
    const int total  = N_NODES * EMB / 4;
    if (i < total) {
        float4 v = (i < uelems) ? ue4[i] : ie4[i - uelems];
        out4[i] = v;
        unsigned int p0 = ((unsigned int)f2bf(v.y) << 16) | f2bf(v.x);
        unsigned int p1 = ((unsigned int)f2bf(v.w) << 16) | f2bf(v.z);
        ebf4[i] = make_uint2(p0, p1);
    }
}

// ---- fused SpMM (bf16 gather, lane=dim) + intent head (bf16-packed W) + combine ----
// Block = 512 (8 waves, 1 row per wave per iter). LDS ~40 KB -> 3 blocks/CU.
// Wtp[c*STW + d/2]: bf16 pair (d,d+1) of W[d][c]   (score phase, lane=intent)
// W2p[d*STV + c/2]: bf16 pair (c,c+1) of W[d][c]   (output phase, lane=dim)
// Both uint2 read patterns are 2-way bank-aliased (free on CDNA4).

__global__ __launch_bounds__(512, 4) void spmm_intent(const int2* __restrict__ rmeta,
                                                      const unsigned int* __restrict__ col,
                                                      const float* __restrict__ dinv,
                                                      const unsigned short* __restrict__ ebf,
                                                      unsigned short* __restrict__ ebfout,
                                                      const float* __restrict__ W,
                                                      float* __restrict__ acc, float scale) {
    __shared__ __align__(16) unsigned int Wtp[NI * STW];   // 17408 B
    __shared__ __align__(16) unsigned int W2p[EMB * STV];  // 16896 B
    __shared__ __align__(16) float pr[8][NI];              // 4096 B
    __shared__ __align__(16) float er[8][EMB];             // 2048 B
    int tid = threadIdx.x;
    // stage packed W (4096 dwords each)
    for (int i = tid; i < 4096; i += 512) {
        int c = i >> 5, d2 = i & 31;
        unsigned int a = f2bf(W[(2 * d2) * NI + c]);
        unsigned int b = f2bf(W[(2 * d2 + 1) * NI + c]);
        Wtp[c * STW + d2] = a | (b << 16);
    }
    for (int i = tid; i < 4096; i += 512) {
        int d = i >> 6, c2 = i & 63;
        unsigned int a = f2bf(W[d * NI + 2 * c2]);
        unsigned int b = f2bf(W[d * NI + 2 * c2 + 1]);
        W2p[d * STV + c2] = a | (b << 16);
    }
    __syncthreads();

    int w = tid >> 6, lane = tid & 63;
    float* erw = er[w];
    float* pw  = pr[w];
    const unsigned int* w0p = &Wtp[lane * STW];
    const unsigned int* w1p = &Wtp[(lane + 64) * STW];
    const unsigned int* w2p = &W2p[lane * STV];

    for (int row = blockIdx.x * 8 + w; row < N_NODES; row += gridDim.x * 8) {
        int2 rm = rmeta[row];
        int s = rm.x, e = rm.x + rm.y;

        // gather: lane = dim, 2B bf16 loads (128 B/wave/edge)
        float a0 = 0.f, a1 = 0.f;
        int i = s;
        for (; i + 3 < e; i += 4) {
            int c0 = col[i], c1 = col[i + 1], c2 = col[i + 2], c3 = col[i + 3];
            float g0 = dinv[c0], g1 = dinv[c1], g2 = dinv[c2], g3 = dinv[c3];
            float v0 = bflo(ebf[((size_t)c0 << 6) + lane]);
            float v1 = bflo(ebf[((size_t)c1 << 6) + lane]);
            float v2 = bflo(ebf[((size_t)c2 << 6) + lane]);
            float v3 = bflo(ebf[((size_t)c3 << 6) + lane]);
            a0 = fmaf(g0, v0, a0); a1 = fmaf(g1, v1, a1);
            a0 = fmaf(g2, v2, a0); a1 = fmaf(g3, v3, a1);
        }
        for (; i < e; ++i) {
            int c0 = col[i];
            a0 = fmaf(dinv[c0], bflo(ebf[((size_t)c0 << 6) + lane]), a0);
        }
        float gnnv = (a0 + a1) * dinv[row];

        // own embedding -> LDS for broadcast
        float eo = bflo(ebf[((size_t)row << 6) + lane]);
        erw[lane] = eo;

        // scores: lane owns intents {lane, lane+64}
        float s0 = 0.f, s1 = 0.f;
#pragma unroll 4
        for (int d = 0; d < EMB; d += 4) {
            float4 ev = *(const float4*)&erw[d];
            uint2 ua = *(const uint2*)&w0p[d >> 1];
            uint2 ub = *(const uint2*)&w1p[d >> 1];
            s0 = fmaf(ev.x, bflo(ua.x), s0); s0 = fmaf(ev.y, bfhi(ua.x), s0);
            s0 = fmaf(ev.z, bflo(ua.y), s0); s0 = fmaf(ev.w, bfhi(ua.y), s0);
            s1 = fmaf(ev.x, bflo(ub.x), s1); s1 = fmaf(ev.y, bfhi(ub.x), s1);
            s1 = fmaf(ev.z, bflo(ub.y), s1); s1 = fmaf(ev.w, bfhi(ub.y), s1);
        }
        float m = fmaxf(s0, s1);
        for (int o = 32; o > 0; o >>= 1) m = fmaxf(m, __shfl_xor(m, o));
        float e0 = __expf(s0 - m), e1 = __expf(s1 - m);
        float sum = e0 + e1;
        for (int o = 32; o > 0; o >>= 1) sum += __shfl_xor(sum, o);
        float inv = 1.0f / sum;
        pw[lane]      = e0 * inv;
        pw[lane + 64] = e1 * inv;

        // output: lane owns dim = lane
        float o = 0.f;
#pragma unroll 4
        for (int c = 0; c < NI; c += 4) {
            float4 pv = *(const float4*)&pw[c];
            uint2 u = *(const uint2*)&w2p[c >> 1];
            o = fmaf(pv.x, bflo(u.x), o); o = fmaf(pv.y, bfhi(u.x), o);
            o = fmaf(pv.z, bflo(u.y), o); o = fmaf(pv.w, bfhi(u.y), o);
        }

        size_t idx = (size_t)row * EMB + lane;
        float nv = gnnv + o;
        ebfout[idx] = f2bf(nv);
        acc[idx] = (acc[idx] + nv) * scale;
    }
}

// ---- launch ----

extern "C" void kernel_launch(void* const* d_in, const int* in_sizes, int n_in,
                              void* d_out, int out_size, void* d_ws, size_t ws_size,
                              hipStream_t stream) {
    const float* ue = (const float*)d_in[0];
    const float* ie = (const float*)d_in[1];
    const float* W  = (const float*)d_in[2];
    const int*   h  = (const int*)d_in[3];
    const int*   t  = (const int*)d_in[4];
    float* out = (float*)d_out;

    // workspace (4-byte units), ~60 MB total
    int*            gcur  = (int*)d_ws;                         // 1024 (NB used)
    int2*           rmeta = (int2*)(gcur + 1024);               // NPAD int2
    float*          dinv  = (float*)(rmeta + NPAD);             // NPAD
    unsigned int*   ebuf  = (unsigned int*)(dinv + NPAD);       // NB*BSTRIDE
    unsigned short* ebfA  = (unsigned short*)(ebuf + NB * BSTRIDE);   // NPAD*64 ushort
    unsigned short* ebfB  = ebfA + (size_t)NPAD * EMB;                // NPAD*64 ushort

    hipMemsetAsync(gcur, 0, NB * sizeof(int), stream);
    bucket_scatter<<<EGRID, 256, 0, stream>>>(h, t, gcur, ebuf);
    bucket_csr<<<NB, 256, 0, stream>>>(gcur, ebuf, rmeta, dinv);
    init_kernel<<<(N_NODES * EMB / 4 + 255) / 256, 256, 0, stream>>>(
        (const float4*)ue, (const float4*)ie, (uint2*)ebfA, (float4*)out);

    const unsigned int* col = ebuf;
    spmm_intent<<<1024, 512, 0, stream>>>(rmeta, col, dinv, ebfA, ebfB, W, out, 1.0f);
    spmm_intent<<<1024, 512, 0, stream>>>(rmeta, col, dinv, ebfB, ebfA, W, out, 1.0f / 3.0f);
}